// Round 6
// baseline (327.266 us; speedup 1.0000x reference)
//
#include <hip/hip_runtime.h>

// LJ pair-energy, round 6: single-sort pipeline.
//  sort pairs by i-bucket (64 buckets x 4096 particles) -> compute serves i
//  from a 48KB LDS slice, j stays a random gather (MSHR-bound, ~45us for
//  8.4M reqs). Scatter redesigned vs R5: single input read, 64 regions
//  (no L2 write thrash), LDS-staged 256B coalesced flushes, spill path.
// Fallback: R3 gather kernel (proven 90us) if shapes/ws don't match.

typedef int   vint4   __attribute__((ext_vector_type(4)));
typedef vint4 vint4u  __attribute__((aligned(4)));      // 4B-aligned int4 loads
typedef float vfloat4 __attribute__((ext_vector_type(4)));
typedef vfloat4 vfloat4u __attribute__((aligned(4)));   // 4B-aligned float4 loads

#define NBKT   64
#define IBITS  12          // bucket = i >> 12 (4096 particles/bucket)
#define CAP    192         // staging capacity per bucket per pass
#define SCB    256         // scatter blocks
#define SCT    1024        // scatter threads
#define OFCAP  8192        // overflow list capacity (expected use: 0)

// ---------------- prep: fused repack (optional) + histogram ----------------
__global__ __launch_bounds__(256) void prep_kernel(
    const float* __restrict__ x, float* __restrict__ xp, int rb,
    const vint4* __restrict__ ii, unsigned* __restrict__ count, int n4, int n3)
{
    if ((int)blockIdx.x < rb) {                 // repack blocks
        int t = blockIdx.x * 256 + threadIdx.x;
        if (t < n3) {
            float v = x[t];
            int p = t / 3;
            int c = t - 3 * p;
            xp[4 * p + c] = v;                  // .w never read
        }
        return;
    }
    // histogram blocks
    __shared__ unsigned h[NBKT];
    if (threadIdx.x < NBKT) h[threadIdx.x] = 0;
    __syncthreads();
    const int hb = blockIdx.x - rb;
    const int nhb = gridDim.x - rb;
    const int stride = nhb * 256;
    for (int s = hb * 256 + threadIdx.x; s < n4; s += stride) {
        vint4 a = __builtin_nontemporal_load(ii + s);
        atomicAdd(&h[a.x >> IBITS], 1u);
        atomicAdd(&h[a.y >> IBITS], 1u);
        atomicAdd(&h[a.z >> IBITS], 1u);
        atomicAdd(&h[a.w >> IBITS], 1u);
    }
    __syncthreads();
    if (threadIdx.x < NBKT) {
        unsigned v = h[threadIdx.x];
        if (v) atomicAdd(&count[threadIdx.x], v);
    }
}

// ---------------- scan: 64-wide exclusive scan (4-aligned starts) ----------
__global__ void scan_kernel(const unsigned* __restrict__ count,
                            unsigned* __restrict__ start,
                            unsigned* __restrict__ gcur,
                            unsigned* __restrict__ ofcnt)
{
    if (threadIdx.x == 0) {
        unsigned a = 0;
        for (int b = 0; b < NBKT; ++b) {
            start[b] = a;
            gcur[b]  = a;
            a += (count[b] + 3u) & ~3u;        // keep every region 4-aligned
        }
        ofcnt[0] = 0;
    }
}

// ---------------- scatter: single-read, LDS-staged, 64 regions -------------
__global__ __launch_bounds__(SCT) void scatter_kernel(
    const vint4* __restrict__ ii, const vint4* __restrict__ jj,
    unsigned* __restrict__ gcur, unsigned* __restrict__ sorted,
    unsigned* __restrict__ ofcnt, int* __restrict__ ofi, int* __restrict__ ofj,
    int n4)
{
    __shared__ unsigned cnt[NBKT];
    __shared__ unsigned base[NBKT];
    __shared__ unsigned stage[NBKT][CAP];       // 48KB

    if (threadIdx.x < NBKT) cnt[threadIdx.x] = 0;
    __syncthreads();

    const int per_pass = SCB * SCT;             // 262144 quads/pass
    for (int pass = 0; pass * per_pass < n4; ++pass) {
        int s = pass * per_pass + blockIdx.x * SCT + threadIdx.x;
        if (s < n4) {
            vint4 a = __builtin_nontemporal_load(ii + s);
            vint4 b = __builtin_nontemporal_load(jj + s);
            const int ia[4] = {a.x, a.y, a.z, a.w};
            const int ja[4] = {b.x, b.y, b.z, b.w};
#pragma unroll
            for (int k = 0; k < 4; ++k) {
                int bk = ia[k] >> IBITS;
                unsigned p = atomicAdd(&cnt[bk], 1u);
                if (p < CAP) {
                    stage[bk][p] = (unsigned)(ia[k] & 4095) |
                                   ((unsigned)ja[k] << IBITS);
                } else {                        // statistically never (CAP=3x mean)
                    unsigned sp = atomicAdd(ofcnt, 1u);
                    if (sp < OFCAP) { ofi[sp] = ia[k]; ofj[sp] = ja[k]; }
                }
            }
        }
        __syncthreads();
        // flush: 16 threads per bucket, coalesced 64B bursts
        const int bk  = threadIdx.x >> 4;
        const int sub = threadIdx.x & 15;
        const unsigned c = min(cnt[bk], (unsigned)CAP);
        if (sub == 0 && c) base[bk] = atomicAdd(&gcur[bk], c);
        __syncthreads();
        const unsigned gb = base[bk];
        for (unsigned e = sub; e < c; e += 16)
            sorted[gb + e] = stage[bk][e];
        __syncthreads();
        if (threadIdx.x < NBKT) cnt[threadIdx.x] = 0;
        __syncthreads();
    }
}

// ---------------- compute: i from LDS slice, j gathered --------------------
// variant A: j from packed float4 table (ws permitting)
__global__ __launch_bounds__(1024) void computeA_kernel(
    const float* __restrict__ x, const float4* __restrict__ xp,
    const float* __restrict__ eps_p, const float* __restrict__ sig_p,
    const float* __restrict__ box_p,
    const unsigned* __restrict__ sorted, const unsigned* __restrict__ start,
    const unsigned* __restrict__ gcur, double* __restrict__ partials)
{
    __shared__ float xi[4096], yi[4096], zi[4096];   // 48KB
    __shared__ double red[16];
    const int b = blockIdx.x >> 2;
    const int q = blockIdx.x & 3;

    // load slice b into LDS (SoA), float4 chunks
    {
        const float4* xb = (const float4*)(x + (size_t)b * 4096 * 3);
        for (int k = threadIdx.x; k < 3072; k += 1024) {
            float4 v = xb[k];
            int flat = 4 * k;
#pragma unroll
            for (int c = 0; c < 4; ++c) {
                int f = flat + c;
                int p = f / 3;
                int comp = f - 3 * p;
                ((comp == 0) ? xi : (comp == 1) ? yi : zi)[p] = (&v.x)[c];
            }
        }
    }
    __syncthreads();

    const float eps  = eps_p[0];
    const float sig  = sig_p[0];
    const float sig2 = sig * sig;
    const float L0 = box_p[0], L1 = box_p[1], L2 = box_p[2];
    const float i0 = 1.0f / L0, i1 = 1.0f / L1, i2 = 1.0f / L2;

    const unsigned sb   = start[b];
    const unsigned cntb = gcur[b] - sb;
    const unsigned qlen = ((cntb + 15u) >> 4) << 2;      // multiple of 4
    const unsigned s0 = sb + q * qlen;
    const unsigned s1 = min(s0 + qlen, sb + cntb);

    float sum = 0.0f;
    for (unsigned basei = s0 + threadIdx.x * 4; basei < s1; basei += 4096) {
        if (basei + 3 < s1) {
            vint4u u4 = __builtin_nontemporal_load((const vint4u*)(sorted + basei));
            const unsigned uu[4] = {(unsigned)u4.x, (unsigned)u4.y,
                                    (unsigned)u4.z, (unsigned)u4.w};
            float4 pj[4];
#pragma unroll
            for (int k = 0; k < 4; ++k) pj[k] = xp[uu[k] >> IBITS];
#pragma unroll
            for (int k = 0; k < 4; ++k) {
                int li = (int)(uu[k] & 4095u);
                float dx = xi[li] - pj[k].x;
                float dy = yi[li] - pj[k].y;
                float dz = zi[li] - pj[k].z;
                dx -= L0 * rintf(dx * i0);
                dy -= L1 * rintf(dy * i1);
                dz -= L2 * rintf(dz * i2);
                const float r2 = dx * dx + dy * dy + dz * dz;
                const float s2 = sig2 / r2;
                const float s6 = s2 * s2 * s2;
                sum += s6 * s6 - s6;
            }
        } else {
            for (unsigned e = basei; e < s1; ++e) {
                unsigned u = sorted[e];
                int li = (int)(u & 4095u);
                float4 pj = xp[u >> IBITS];
                float dx = xi[li] - pj.x;
                float dy = yi[li] - pj.y;
                float dz = zi[li] - pj.z;
                dx -= L0 * rintf(dx * i0);
                dy -= L1 * rintf(dy * i1);
                dz -= L2 * rintf(dz * i2);
                const float r2 = dx * dx + dy * dy + dz * dz;
                const float s2 = sig2 / r2;
                const float s6 = s2 * s2 * s2;
                sum += s6 * s6 - s6;
            }
        }
    }
    double dsum = (double)(4.0f * eps * sum);
#pragma unroll
    for (int off = 32; off > 0; off >>= 1)
        dsum += __shfl_down(dsum, off, 64);
    if ((threadIdx.x & 63) == 0) red[threadIdx.x >> 6] = dsum;
    __syncthreads();
    if (threadIdx.x == 0) {
        double t = 0.0;
        for (int w = 0; w < 16; ++w) t += red[w];
        partials[blockIdx.x] = t;
    }
}

// variant B: j straight from x (12B stride, 4B-aligned dwordx4 w/ edge guard)
__global__ __launch_bounds__(1024) void computeB_kernel(
    const float* __restrict__ x,
    const float* __restrict__ eps_p, const float* __restrict__ sig_p,
    const float* __restrict__ box_p,
    const unsigned* __restrict__ sorted, const unsigned* __restrict__ start,
    const unsigned* __restrict__ gcur, double* __restrict__ partials,
    int n_part)
{
    __shared__ float xi[4096], yi[4096], zi[4096];
    __shared__ double red[16];
    const int b = blockIdx.x >> 2;
    const int q = blockIdx.x & 3;
    {
        const float4* xb = (const float4*)(x + (size_t)b * 4096 * 3);
        for (int k = threadIdx.x; k < 3072; k += 1024) {
            float4 v = xb[k];
            int flat = 4 * k;
#pragma unroll
            for (int c = 0; c < 4; ++c) {
                int f = flat + c;
                int p = f / 3;
                int comp = f - 3 * p;
                ((comp == 0) ? xi : (comp == 1) ? yi : zi)[p] = (&v.x)[c];
            }
        }
    }
    __syncthreads();

    const float eps  = eps_p[0];
    const float sig  = sig_p[0];
    const float sig2 = sig * sig;
    const float L0 = box_p[0], L1 = box_p[1], L2 = box_p[2];
    const float i0 = 1.0f / L0, i1 = 1.0f / L1, i2 = 1.0f / L2;

    const unsigned sb   = start[b];
    const unsigned cntb = gcur[b] - sb;
    const unsigned qlen = ((cntb + 15u) >> 4) << 2;
    const unsigned s0 = sb + q * qlen;
    const unsigned s1 = min(s0 + qlen, sb + cntb);
    const int last = n_part - 1;

    float sum = 0.0f;
    for (unsigned basei = s0 + threadIdx.x * 4; basei < s1; basei += 4096) {
        unsigned lim = min(basei + 4, s1);
        for (unsigned e = basei; e < lim; ++e) {
            unsigned u = sorted[e];
            int li = (int)(u & 4095u);
            int j = (int)(u >> IBITS);
            float jx, jy, jz;
            if (j < last) {
                vfloat4u pj = *(const vfloat4u*)(x + 3 * j);
                jx = pj.x; jy = pj.y; jz = pj.z;
            } else {
                jx = x[3*j]; jy = x[3*j+1]; jz = x[3*j+2];
            }
            float dx = xi[li] - jx;
            float dy = yi[li] - jy;
            float dz = zi[li] - jz;
            dx -= L0 * rintf(dx * i0);
            dy -= L1 * rintf(dy * i1);
            dz -= L2 * rintf(dz * i2);
            const float r2 = dx * dx + dy * dy + dz * dz;
            const float s2 = sig2 / r2;
            const float s6 = s2 * s2 * s2;
            sum += s6 * s6 - s6;
        }
    }
    double dsum = (double)(4.0f * eps * sum);
#pragma unroll
    for (int off = 32; off > 0; off >>= 1)
        dsum += __shfl_down(dsum, off, 64);
    if ((threadIdx.x & 63) == 0) red[threadIdx.x >> 6] = dsum;
    __syncthreads();
    if (threadIdx.x == 0) {
        double t = 0.0;
        for (int w = 0; w < 16; ++w) t += red[w];
        partials[blockIdx.x] = t;
    }
}

// ---------------- finalize: partials + overflow list -----------------------
__global__ __launch_bounds__(1024) void finalize_kernel(
    const double* __restrict__ partials, int np,
    const unsigned* __restrict__ ofcnt,
    const int* __restrict__ ofi, const int* __restrict__ ofj,
    const float* __restrict__ x,
    const float* __restrict__ eps_p, const float* __restrict__ sig_p,
    const float* __restrict__ box_p, float* __restrict__ out)
{
    const float eps  = eps_p[0];
    const float sig  = sig_p[0];
    const float sig2 = sig * sig;
    const float L0 = box_p[0], L1 = box_p[1], L2 = box_p[2];
    const float i0 = 1.0f / L0, i1 = 1.0f / L1, i2 = 1.0f / L2;

    double s = 0.0;
    for (int i = threadIdx.x; i < np; i += 1024) s += partials[i];
    const int oc = (int)min(ofcnt[0], (unsigned)OFCAP);
    for (int t = threadIdx.x; t < oc; t += 1024) {
        int i = ofi[t], j = ofj[t];
        float dx = x[3*i]   - x[3*j];
        float dy = x[3*i+1] - x[3*j+1];
        float dz = x[3*i+2] - x[3*j+2];
        dx -= L0 * rintf(dx * i0);
        dy -= L1 * rintf(dy * i1);
        dz -= L2 * rintf(dz * i2);
        const float r2 = dx * dx + dy * dy + dz * dz;
        const float s2 = sig2 / r2;
        const float s6 = s2 * s2 * s2;
        s += (double)(4.0f * eps * (s6 * s6 - s6));
    }
#pragma unroll
    for (int off = 32; off > 0; off >>= 1)
        s += __shfl_down(s, off, 64);
    __shared__ double red[16];
    if ((threadIdx.x & 63) == 0) red[threadIdx.x >> 6] = s;
    __syncthreads();
    if (threadIdx.x == 0) {
        double t = 0.0;
        for (int w = 0; w < 16; ++w) t += red[w];
        out[0] = (float)t;
    }
}

// ---------------- fallback: R3 (proven 90us) -------------------------------
__global__ __launch_bounds__(256) void repack_kernel(
    const float* __restrict__ x, float* __restrict__ xp, int n3)
{
    int t = blockIdx.x * 256 + threadIdx.x;
    if (t < n3) {
        float v = x[t];
        int p = t / 3;
        int c = t - 3 * p;
        xp[4 * p + c] = v;
    }
}

__global__ __launch_bounds__(256) void lj_pairs4_kernel(
    const float4* __restrict__ xp, const float* __restrict__ eps_p,
    const float* __restrict__ sig_p, const float* __restrict__ box_p,
    const vint4* __restrict__ idx_i4, const vint4* __restrict__ idx_j4,
    double* __restrict__ partial)
{
    const int t = blockIdx.x * blockDim.x + threadIdx.x;
    const float eps  = eps_p[0];
    const float sig  = sig_p[0];
    const float sig2 = sig * sig;
    const float L0 = box_p[0], L1 = box_p[1], L2 = box_p[2];
    const float i0 = 1.0f / L0, i1 = 1.0f / L1, i2 = 1.0f / L2;
    const vint4 ii = __builtin_nontemporal_load(idx_i4 + t);
    const vint4 jj = __builtin_nontemporal_load(idx_j4 + t);
    const int ia[4] = {ii.x, ii.y, ii.z, ii.w};
    const int ja[4] = {jj.x, jj.y, jj.z, jj.w};
    float sum = 0.0f;
#pragma unroll
    for (int k = 0; k < 4; ++k) {
        const float4 pi = xp[ia[k]];
        const float4 pj = xp[ja[k]];
        float dx = pi.x - pj.x;
        float dy = pi.y - pj.y;
        float dz = pi.z - pj.z;
        dx -= L0 * rintf(dx * i0);
        dy -= L1 * rintf(dy * i1);
        dz -= L2 * rintf(dz * i2);
        const float r2 = dx * dx + dy * dy + dz * dz;
        const float s2 = sig2 / r2;
        const float s6 = s2 * s2 * s2;
        sum += s6 * s6 - s6;
    }
    double dsum = (double)(4.0f * eps * sum);
#pragma unroll
    for (int off = 32; off > 0; off >>= 1)
        dsum += __shfl_down(dsum, off, 64);
    __shared__ double wsum[4];
    if ((threadIdx.x & 63) == 0) wsum[threadIdx.x >> 6] = dsum;
    __syncthreads();
    if (threadIdx.x == 0)
        partial[blockIdx.x] = wsum[0] + wsum[1] + wsum[2] + wsum[3];
}

__global__ __launch_bounds__(256) void reduce_kernel(
    const double* __restrict__ partial, int n, float* __restrict__ out)
{
    double s = 0.0;
    for (int i = threadIdx.x; i < n; i += 256) s += partial[i];
#pragma unroll
    for (int off = 32; off > 0; off >>= 1)
        s += __shfl_down(s, off, 64);
    __shared__ double wsum[4];
    if ((threadIdx.x & 63) == 0) wsum[threadIdx.x >> 6] = s;
    __syncthreads();
    if (threadIdx.x == 0)
        out[0] = (float)(wsum[0] + wsum[1] + wsum[2] + wsum[3]);
}

// ---------------------------------------------------------------------------
extern "C" void kernel_launch(void* const* d_in, const int* in_sizes, int n_in,
                              void* d_out, int out_size, void* d_ws, size_t ws_size,
                              hipStream_t stream) {
    const float* x     = (const float*)d_in[0];
    const float* eps   = (const float*)d_in[1];
    const float* sigma = (const float*)d_in[2];
    const float* box   = (const float*)d_in[3];
    const vint4* ii    = (const vint4*)d_in[4];
    const vint4* jj    = (const vint4*)d_in[5];
    float* out = (float*)d_out;

    const int n_pairs = in_sizes[4];
    const int n_part  = in_sizes[0] / 3;

    // ws layout
    const size_t OFF_SORTED = 0;
    const size_t SZ_SORTED  = (size_t)n_pairs * 4 + 1024;       // + align pad
    const size_t OFF_COUNT  = (SZ_SORTED + 255) & ~(size_t)255; // 64*4
    const size_t OFF_START  = OFF_COUNT + 256;                  // 64*4
    const size_t OFF_GCUR   = OFF_START + 256;                  // 64*4
    const size_t OFF_OFCNT  = OFF_GCUR + 256;                   // 4
    const size_t OFF_OFI    = OFF_OFCNT + 256;                  // OFCAP*4
    const size_t OFF_OFJ    = OFF_OFI + OFCAP * 4;
    const size_t OFF_PART   = OFF_OFJ + OFCAP * 4;              // 256*8
    const size_t NEED_BASE  = OFF_PART + 256 * 8;
    const size_t OFF_XP     = (NEED_BASE + 255) & ~(size_t)255;
    const size_t NEED_XP    = OFF_XP + (size_t)n_part * 16;

    const bool shapes_ok = (n_part == 262144) && (n_pairs == 8388608);
    const bool base_ok   = shapes_ok && (ws_size >= NEED_BASE);
    const bool xp_ok     = shapes_ok && (ws_size >= NEED_XP);

    if (base_ok) {
        unsigned* sorted  = (unsigned*)((char*)d_ws + OFF_SORTED);
        unsigned* count   = (unsigned*)((char*)d_ws + OFF_COUNT);
        unsigned* start   = (unsigned*)((char*)d_ws + OFF_START);
        unsigned* gcur    = (unsigned*)((char*)d_ws + OFF_GCUR);
        unsigned* ofcnt   = (unsigned*)((char*)d_ws + OFF_OFCNT);
        int*      ofi     = (int*)     ((char*)d_ws + OFF_OFI);
        int*      ofj     = (int*)     ((char*)d_ws + OFF_OFJ);
        double*   partials= (double*)  ((char*)d_ws + OFF_PART);
        float*    xp      = xp_ok ? (float*)((char*)d_ws + OFF_XP) : nullptr;
        const int n4 = n_pairs / 4;
        const int n3 = n_part * 3;
        const int rb = xp_ok ? (n3 + 255) / 256 : 0;   // 3072 repack blocks

        hipMemsetAsync(count, 0, 256, stream);
        prep_kernel<<<rb + 256, 256, 0, stream>>>(x, xp, rb, ii, count, n4, n3);
        scan_kernel<<<1, 64, 0, stream>>>(count, start, gcur, ofcnt);
        scatter_kernel<<<SCB, SCT, 0, stream>>>(ii, jj, gcur, sorted,
                                                ofcnt, ofi, ofj, n4);
        if (xp_ok)
            computeA_kernel<<<256, 1024, 0, stream>>>(
                x, (const float4*)xp, eps, sigma, box, sorted, start, gcur, partials);
        else
            computeB_kernel<<<256, 1024, 0, stream>>>(
                x, eps, sigma, box, sorted, start, gcur, partials, n_part);
        finalize_kernel<<<1, 1024, 0, stream>>>(partials, 256, ofcnt, ofi, ofj,
                                                x, eps, sigma, box, out);
        return;
    }

    // fallback: R3 path
    const int block = 256;
    const int grid = (n_pairs / 4) / block;
    const size_t packed_bytes = (size_t)n_part * 16;
    float4* xp = (float4*)d_ws;
    double* partial = (double*)((char*)d_ws + packed_bytes);
    const int n3 = n_part * 3;
    repack_kernel<<<(n3 + block - 1) / block, block, 0, stream>>>(x, (float*)xp, n3);
    lj_pairs4_kernel<<<grid, block, 0, stream>>>(xp, eps, sigma, box, ii, jj, partial);
    reduce_kernel<<<1, block, 0, stream>>>(partial, grid, out);
}